// Round 1
// baseline (167.355 us; speedup 1.0000x reference)
//
#include <hip/hip_runtime.h>
#include <hip/hip_bf16.h>
#include <math.h>

#define B    64
#define L1   199
#define L    200
#define NC   1000
#define D    64
#define M    50
#define NCH  10     // m-chunks in the scan
#define MC   5      // m per chunk (NCH*MC = M)
#define TCC  50     // time-chunk per scan stage (L/TCC = 4)

__device__ __forceinline__ float readlane_f(float v, int lane) {
    return __uint_as_float(__builtin_amdgcn_readlane(__float_as_uint(v), lane));
}

// ---------------- Phase 1, role-split: 4800 single-wave blocks.
// role 0: w = softmax(k@Mk^T)   lane=m;    Mk row in VGPR, k row via SCALAR loads
// role 1: e = sigmoid(v@We+be)  lane=dout; We column in VGPR, v row via SCALAR loads
// role 2: a = tanh(v@Wa+ba)     lane=dout; Wa column in VGPR, v row via SCALAR loads
// Broadcast operand comes from SGPRs (s_load of uniform-address row) ->
// v_fmac with SGPR src: 1 VALU issue per MAC, no readlane, no hazard nops.
__global__ __launch_bounds__(64) void phase1(
    const int* __restrict__ cseqs, const int* __restrict__ rseqs,
    const int* __restrict__ shft_cseqs, const int* __restrict__ shft_rseqs,
    const float* __restrict__ kemb, const float* __restrict__ vemb,
    const float* __restrict__ Mk, const float* __restrict__ We,
    const float* __restrict__ be, const float* __restrict__ Wa,
    const float* __restrict__ ba,
    float* __restrict__ w_out, float* __restrict__ e_out, float* __restrict__ a_out)
{
    const int lane = threadIdx.x;
    const int bid  = blockIdx.x;
    const int role = bid % 3;        // 0=w, 1=e, 2=a
    const int base = (bid / 3) * 8;  // 1600 waves per role * 8 = 12800 positions

    // indices for all 8 positions (wave-uniform; force into SGPRs)
    int q8[8], x8[8];
    #pragma unroll
    for (int p = 0; p < 8; ++p) {
        const int gpos = base + p;
        const int b = gpos / L, l = gpos % L;
        int q, r;
        if (l == 0) { q = cseqs[b * L1];              r = rseqs[b * L1]; }
        else        { q = shft_cseqs[b * L1 + l - 1]; r = shft_rseqs[b * L1 + l - 1]; }
        q8[p] = __builtin_amdgcn_readfirstlane(q);
        x8[p] = __builtin_amdgcn_readfirstlane(q + NC * r);
    }

    if (role != 0) {
        // ---- e or a: lane = d_out; weight column register-resident
        const float* __restrict__ W  = (role == 1) ? We : Wa;
        const float* __restrict__ bb = (role == 1) ? be : ba;
        float*       __restrict__ dst = (role == 1) ? e_out : a_out;

        float Wc[D];
        #pragma unroll
        for (int din = 0; din < D; ++din) Wc[din] = W[din * D + lane];
        const float br = bb[lane];

        #pragma unroll
        for (int p = 0; p < 8; ++p) {
            // uniform address -> scalar loads into SGPRs
            const float* __restrict__ vrow = vemb + (size_t)x8[p] * D;
            float c0 = 0.f, c1 = 0.f;
            #pragma unroll
            for (int din = 0; din < D; din += 2) {
                c0 = fmaf(Wc[din],     vrow[din],     c0);
                c1 = fmaf(Wc[din + 1], vrow[din + 1], c1);
            }
            const float acc = c0 + c1;
            const float r = (role == 1) ? (1.f / (1.f + expf(-(acc + br))))
                                        : tanhf(acc + br);
            dst[(size_t)(base + p) * D + lane] = r;
        }
    } else {
        // ---- w: lane = m; Mk row register-resident, k row via scalar loads
        float Mk_r[D];
        {
            const int mrow = (lane < M) ? lane : (M - 1);
            #pragma unroll
            for (int d = 0; d < D; d += 4) {
                const float4 t4 = *(const float4*)(Mk + mrow * D + d);
                Mk_r[d] = t4.x; Mk_r[d+1] = t4.y; Mk_r[d+2] = t4.z; Mk_r[d+3] = t4.w;
            }
        }
        #pragma unroll
        for (int p = 0; p < 8; ++p) {
            const float* __restrict__ krow = kemb + (size_t)q8[p] * D;
            float c0 = 0.f, c1 = 0.f;
            #pragma unroll
            for (int d = 0; d < D; d += 2) {
                c0 = fmaf(Mk_r[d],     krow[d],     c0);
                c1 = fmaf(Mk_r[d + 1], krow[d + 1], c1);
            }
            const float logit = (lane < M) ? (c0 + c1) : -INFINITY;
            float mx = logit;
            #pragma unroll
            for (int off = 32; off; off >>= 1) mx = fmaxf(mx, __shfl_xor(mx, off, 64));
            const float ex = expf(logit - mx);
            float sm = ex;
            #pragma unroll
            for (int off = 32; off; off >>= 1) sm += __shfl_xor(sm, off, 64);
            if (lane < M) w_out[(size_t)(base + p) * M + lane] = ex / sm;
        }
    }
}

// ---------------- Phase 2: the scan. One single-wave block per (b, m-chunk).
// lane = d. Mv in registers; w row per t via SCALAR loads (uniform address).
__global__ __launch_bounds__(64, 1) void phase2(
    const float* __restrict__ Mv0,
    const float* __restrict__ w_in, const float* __restrict__ e_in,
    const float* __restrict__ a_in, float* __restrict__ rp_out)
{
    const int lane = threadIdx.x;
    const int b  = blockIdx.x / NCH;
    const int ch = blockIdx.x % NCH;
    const int m0 = ch * MC;

    float Mv[MC];
    #pragma unroll
    for (int j = 0; j < MC; ++j) Mv[j] = Mv0[(m0 + j) * D + lane];

    const float* __restrict__ eb = e_in + (size_t)b * L * D + lane;
    const float* __restrict__ ab = a_in + (size_t)b * L * D + lane;
    const float* __restrict__ wb = w_in + (size_t)b * L * M + m0;
    float* __restrict__ rp = rp_out + ((size_t)b * L * NCH + ch) * D + lane;

    for (int tcb = 0; tcb < L / TCC; ++tcb) {
        const int t0 = tcb * TCC;

        float er[TCC], ar[TCC];
        #pragma unroll
        for (int t = 0; t < TCC; ++t) {
            er[t] = eb[(t0 + t) * D];
            ar[t] = ab[(t0 + t) * D];
        }

        #pragma unroll
        for (int t = 0; t < TCC; ++t) {
            const float* __restrict__ wr = wb + (size_t)(t0 + t) * M;  // uniform -> s_load
            const float ed = er[t], ad = ar[t];
            float r0 = 0.f, r1 = 0.f;
            #pragma unroll
            for (int j = 0; j < MC; ++j) {
                const float wm = wr[j];                    // SGPR broadcast
                if (j & 1) r1 = fmaf(wm, Mv[j], r1);
                else       r0 = fmaf(wm, Mv[j], r0);       // read BEFORE update
                Mv[j] = fmaf(Mv[j], -(wm * ed), fmaf(wm, ad, Mv[j]));  // Mv*(1-we) + wm*ad
            }
            rp[(size_t)(t0 + t) * NCH * D] = r0 + r1;
        }
    }
}

// ---------------- Phase 3: read = sum partials; f = tanh([read,k]@Wf+bf); p = sigmoid(f@Wp+bp)
// 800 blocks x 256; Wf register-resident; k row via scalar loads; rd via readlane.
__global__ __launch_bounds__(256, 1) void phase3(
    const int* __restrict__ cseqs, const int* __restrict__ shft_cseqs,
    const float* __restrict__ kemb,
    const float* __restrict__ Wf, const float* __restrict__ bf,
    const float* __restrict__ Wp, const float* __restrict__ bp,
    const float* __restrict__ rp, float* __restrict__ out)
{
    const int tid  = threadIdx.x;
    const int lane = tid & 63;
    const int wave = tid >> 6;

    float Wf_c[2 * D];
    #pragma unroll
    for (int i = 0; i < 2 * D; ++i) Wf_c[i] = Wf[i * D + lane];
    const float bf_r = bf[lane];
    const float wp_r = Wp[lane];
    const float bp_r = bp[0];

    const int base = blockIdx.x * 16 + wave * 4;   // 800*16 = 12800

    int q4[4];
    #pragma unroll
    for (int p = 0; p < 4; ++p) {
        const int gpos = base + p;
        const int b = gpos / L, l = gpos % L;
        const int q = (l == 0) ? cseqs[b * L1] : shft_cseqs[b * L1 + l - 1];
        q4[p] = __builtin_amdgcn_readfirstlane(q);
    }

    #pragma unroll
    for (int p = 0; p < 4; ++p) {
        const int gpos = base + p;
        const float* __restrict__ krow = kemb + (size_t)q4[p] * D;  // uniform -> s_load
        float rd = 0.f;
        #pragma unroll
        for (int ch = 0; ch < NCH; ++ch)
            rd += rp[((size_t)gpos * NCH + ch) * D + lane];

        float f0 = 0.f, f1 = 0.f;
        #pragma unroll
        for (int i = 0; i < D; ++i) {
            f0 = fmaf(Wf_c[i],     readlane_f(rd, i), f0);  // rd is computed -> readlane
            f1 = fmaf(Wf_c[D + i], krow[i],           f1);  // SGPR broadcast
        }
        const float f = tanhf(f0 + f1 + bf_r);

        float c = f * wp_r;
        #pragma unroll
        for (int off = 32; off; off >>= 1) c += __shfl_xor(c, off, 64);
        if (lane == 0) out[gpos] = 1.f / (1.f + expf(-(c + bp_r)));
    }
}

extern "C" void kernel_launch(void* const* d_in, const int* in_sizes, int n_in,
                              void* d_out, int out_size, void* d_ws, size_t ws_size,
                              hipStream_t stream) {
    const int*   cseqs      = (const int*)d_in[0];
    const int*   rseqs      = (const int*)d_in[1];
    const int*   shft_cseqs = (const int*)d_in[2];
    const int*   shft_rseqs = (const int*)d_in[3];
    const float* kemb = (const float*)d_in[4];
    const float* vemb = (const float*)d_in[5];
    const float* Mk   = (const float*)d_in[6];
    const float* Mv0  = (const float*)d_in[7];
    const float* Wf   = (const float*)d_in[8];
    const float* bf   = (const float*)d_in[9];
    const float* We   = (const float*)d_in[10];
    const float* be   = (const float*)d_in[11];
    const float* Wa   = (const float*)d_in[12];
    const float* ba   = (const float*)d_in[13];
    const float* Wp   = (const float*)d_in[14];
    const float* bp   = (const float*)d_in[15];
    float* out = (float*)d_out;

    float* ws    = (float*)d_ws;
    float* ws_w  = ws;                        // B*L*M       =   640000 floats
    float* ws_e  = ws_w + (size_t)B * L * M;  // B*L*D       =   819200
    float* ws_a  = ws_e + (size_t)B * L * D;  // B*L*D       =   819200
    float* ws_rp = ws_a + (size_t)B * L * D;  // B*L*NCH*D   =  8192000
    // total ~42 MB of workspace

    phase1<<<dim3(4800), dim3(64), 0, stream>>>(
        cseqs, rseqs, shft_cseqs, shft_rseqs, kemb, vemb,
        Mk, We, be, Wa, ba, ws_w, ws_e, ws_a);
    phase2<<<dim3(B * NCH), dim3(64), 0, stream>>>(Mv0, ws_w, ws_e, ws_a, ws_rp);
    phase3<<<dim3(800), dim3(256), 0, stream>>>(
        cseqs, shft_cseqs, kemb, Wf, bf, Wp, bp, ws_rp, out);
}

// Round 2
// 127.829 us; speedup vs baseline: 1.3092x; 1.3092x over previous
//
#include <hip/hip_runtime.h>
#include <math.h>

#define B    64
#define L1   199
#define L    200
#define NC   1000
#define D    64
#define M    50
#define NCH  10     // m-chunks in the scan
#define MC   5      // m per chunk (NCH*MC = M)
#define TCC  50     // time-chunk per scan stage (L/TCC = 4)

// ---------------- Phase 0: build id-indexed tables (token-id -> row).
// w/e/a/k-half depend only on token ids (q in [0,1000), x in [0,2000)),
// not on positions: 6000 distinct rows instead of 12800 positions.
// Block ranges (4 rows per single-wave block):
//   [0,250):     wtab[q][m]  = softmax(kemb[q] @ Mk^T)
//   [250,750):   etab[x][d]  = sigmoid(vemb[x] @ We + be)
//   [750,1250):  atab[x][d]  = tanh   (vemb[x] @ Wa + ba)
//   [1250,1500): ktab[q][d]  = kemb[q] @ Wf[D:2D]   (phase3 k-half, bias later)
__global__ __launch_bounds__(64) void phase0(
    const float* __restrict__ kemb, const float* __restrict__ vemb,
    const float* __restrict__ Mk,
    const float* __restrict__ We, const float* __restrict__ be,
    const float* __restrict__ Wa, const float* __restrict__ ba,
    const float* __restrict__ Wf,
    float* __restrict__ wtab, float* __restrict__ etab,
    float* __restrict__ atab, float* __restrict__ ktab)
{
    __shared__ __align__(16) float lrow[4 * D];
    const int lane = threadIdx.x;
    const int bid  = blockIdx.x;

    if (bid < 250) {
        // ---- wtab: lane = m; Mk row register-resident; k row via LDS broadcast
        const int r0 = bid * 4;
        #pragma unroll
        for (int i = 0; i < 4; ++i)
            lrow[i * D + lane] = kemb[(size_t)(r0 + i) * D + lane];
        __syncthreads();

        float Mk_r[D];
        {
            const int mrow = (lane < M) ? lane : (M - 1);
            #pragma unroll
            for (int d = 0; d < D; d += 4) {
                const float4 t4 = *(const float4*)(Mk + mrow * D + d);
                Mk_r[d] = t4.x; Mk_r[d+1] = t4.y; Mk_r[d+2] = t4.z; Mk_r[d+3] = t4.w;
            }
        }
        #pragma unroll
        for (int i = 0; i < 4; ++i) {
            float c0 = 0.f, c1 = 0.f;
            #pragma unroll
            for (int d = 0; d < D; d += 4) {   // same even/odd chains as before
                const float4 kb = *(const float4*)&lrow[i * D + d];
                c0 = fmaf(Mk_r[d],     kb.x, c0);
                c1 = fmaf(Mk_r[d + 1], kb.y, c1);
                c0 = fmaf(Mk_r[d + 2], kb.z, c0);
                c1 = fmaf(Mk_r[d + 3], kb.w, c1);
            }
            const float logit = (lane < M) ? (c0 + c1) : -INFINITY;
            float mx = logit;
            #pragma unroll
            for (int off = 32; off; off >>= 1) mx = fmaxf(mx, __shfl_xor(mx, off, 64));
            const float ex = expf(logit - mx);
            float sm = ex;
            #pragma unroll
            for (int off = 32; off; off >>= 1) sm += __shfl_xor(sm, off, 64);
            if (lane < M) wtab[(size_t)(r0 + i) * M + lane] = ex / sm;
        }
    } else if (bid < 1250) {
        // ---- etab / atab: lane = d_out; weight column register-resident
        const bool is_e = (bid < 750);
        const int  r0   = (is_e ? (bid - 250) : (bid - 750)) * 4;
        #pragma unroll
        for (int i = 0; i < 4; ++i)
            lrow[i * D + lane] = vemb[(size_t)(r0 + i) * D + lane];
        __syncthreads();

        const float* __restrict__ W   = is_e ? We : Wa;
        float*       __restrict__ dst = is_e ? etab : atab;
        float Wc[D];
        #pragma unroll
        for (int din = 0; din < D; ++din) Wc[din] = W[din * D + lane];
        const float br = is_e ? be[lane] : ba[lane];

        #pragma unroll
        for (int i = 0; i < 4; ++i) {
            float c0 = 0.f, c1 = 0.f;
            #pragma unroll
            for (int d = 0; d < D; d += 4) {
                const float4 vb = *(const float4*)&lrow[i * D + d];
                c0 = fmaf(Wc[d],     vb.x, c0);
                c1 = fmaf(Wc[d + 1], vb.y, c1);
                c0 = fmaf(Wc[d + 2], vb.z, c0);
                c1 = fmaf(Wc[d + 3], vb.w, c1);
            }
            const float acc = c0 + c1;
            const float r = is_e ? (1.f / (1.f + expf(-(acc + br))))
                                 : tanhf(acc + br);
            dst[(size_t)(r0 + i) * D + lane] = r;
        }
    } else {
        // ---- ktab: lane = d_out; Wf second-half column register-resident
        const int r0 = (bid - 1250) * 4;
        #pragma unroll
        for (int i = 0; i < 4; ++i)
            lrow[i * D + lane] = kemb[(size_t)(r0 + i) * D + lane];
        __syncthreads();

        float Wc[D];
        #pragma unroll
        for (int i = 0; i < D; ++i) Wc[i] = Wf[(size_t)(D + i) * D + lane];

        #pragma unroll
        for (int i = 0; i < 4; ++i) {
            float f1 = 0.f;   // single ascending chain (matches old phase3 f1)
            #pragma unroll
            for (int d = 0; d < D; d += 4) {
                const float4 kb = *(const float4*)&lrow[i * D + d];
                f1 = fmaf(Wc[d],     kb.x, f1);
                f1 = fmaf(Wc[d + 1], kb.y, f1);
                f1 = fmaf(Wc[d + 2], kb.z, f1);
                f1 = fmaf(Wc[d + 3], kb.w, f1);
            }
            ktab[(size_t)(r0 + i) * D + lane] = f1;
        }
    }
}

// ---------------- Phase 2: the scan. One single-wave block per (b, m-chunk).
// lane = d. Mv in registers. Per 50-t chunk: w rows gathered to LDS once
// (read back as uniform ds_read_b128 broadcast -> no per-t memory wait),
// e/a rows fetched via readlane(x_t) -> SGPR base (address math on SALU).
__global__ __launch_bounds__(64, 1) void phase2(
    const float* __restrict__ Mv0,
    const int* __restrict__ cseqs, const int* __restrict__ rseqs,
    const int* __restrict__ shft_cseqs, const int* __restrict__ shft_rseqs,
    const float* __restrict__ wtab, const float* __restrict__ etab,
    const float* __restrict__ atab, float* __restrict__ rp_out)
{
    __shared__ __align__(16) float lds_w[TCC * 8];
    const int lane = threadIdx.x;
    const int b  = blockIdx.x / NCH;
    const int ch = blockIdx.x % NCH;
    const int m0 = ch * MC;

    float Mv[MC];
    #pragma unroll
    for (int j = 0; j < MC; ++j) Mv[j] = Mv0[(m0 + j) * D + lane];

    float* __restrict__ rp = rp_out + ((size_t)b * L * NCH + ch) * D + lane;

    for (int tcb = 0; tcb < L / TCC; ++tcb) {
        const int t0 = tcb * TCC;

        // per-lane token ids for t = t0 + lane (lane < TCC)
        int ql = 0, xl = 0;
        if (lane < TCC) {
            const int t = t0 + lane;
            int q, r;
            if (t == 0) { q = cseqs[b * L1];              r = rseqs[b * L1]; }
            else        { q = shft_cseqs[b * L1 + t - 1]; r = shft_rseqs[b * L1 + t - 1]; }
            ql = q; xl = q + NC * r;
        }
        // stage w rows into LDS (gather via per-lane q)
        if (lane < TCC) {
            const float* __restrict__ wp = wtab + (size_t)ql * M + m0;
            #pragma unroll
            for (int j = 0; j < MC; ++j) lds_w[lane * 8 + j] = wp[j];
        }
        // e/a rows: scalar row index via readlane -> coalesced 256B row loads
        float er[TCC], ar[TCC];
        #pragma unroll
        for (int t = 0; t < TCC; ++t) {
            const int s = __builtin_amdgcn_readlane(xl, t);
            er[t] = etab[(size_t)s * D + lane];
            ar[t] = atab[(size_t)s * D + lane];
        }
        __syncthreads();   // ds_writes visible; drains staging loads

        #pragma unroll
        for (int t = 0; t < TCC; ++t) {
            const float4 w4 = *(const float4*)&lds_w[t * 8];  // uniform -> broadcast
            const float  wm0 = w4.x, wm1 = w4.y, wm2 = w4.z, wm3 = w4.w;
            const float  wm4 = lds_w[t * 8 + 4];
            const float ed = er[t], ad = ar[t];
            float r0 = 0.f, r1 = 0.f;
            // exact same even/odd accumulation + update form as the passing kernel
            r0 = fmaf(wm0, Mv[0], r0); Mv[0] = fmaf(Mv[0], -(wm0 * ed), fmaf(wm0, ad, Mv[0]));
            r1 = fmaf(wm1, Mv[1], r1); Mv[1] = fmaf(Mv[1], -(wm1 * ed), fmaf(wm1, ad, Mv[1]));
            r0 = fmaf(wm2, Mv[2], r0); Mv[2] = fmaf(Mv[2], -(wm2 * ed), fmaf(wm2, ad, Mv[2]));
            r1 = fmaf(wm3, Mv[3], r1); Mv[3] = fmaf(Mv[3], -(wm3 * ed), fmaf(wm3, ad, Mv[3]));
            r0 = fmaf(wm4, Mv[4], r0); Mv[4] = fmaf(Mv[4], -(wm4 * ed), fmaf(wm4, ad, Mv[4]));
            rp[(size_t)(t0 + t) * NCH * D] = r0 + r1;
        }
        // WAR on lds_w across chunks is safe: DS ops of one wave execute in order.
    }
}

// ---------------- Phase 3: read = sum partials; f = tanh(read@Wf1 + ktab[q] + bf);
// p = sigmoid(f@Wp+bp). rd broadcast via per-wave LDS row (ds_read_b128 uniform).
__global__ __launch_bounds__(256, 1) void phase3(
    const int* __restrict__ cseqs, const int* __restrict__ shft_cseqs,
    const float* __restrict__ ktab,
    const float* __restrict__ Wf, const float* __restrict__ bf,
    const float* __restrict__ Wp, const float* __restrict__ bp,
    const float* __restrict__ rp, float* __restrict__ out)
{
    __shared__ __align__(16) float lds_rd[4 * D];
    const int tid  = threadIdx.x;
    const int lane = tid & 63;
    const int wave = tid >> 6;
    float* __restrict__ lrd = lds_rd + wave * D;   // wave-private region

    float Wf_c[D];   // first-half columns only (k-half folded into ktab)
    #pragma unroll
    for (int i = 0; i < D; ++i) Wf_c[i] = Wf[(size_t)i * D + lane];
    const float bf_r = bf[lane];
    const float wp_r = Wp[lane];
    const float bp_r = bp[0];

    const int base = blockIdx.x * 16 + wave * 4;   // 800*16 = 12800

    int q4[4];
    #pragma unroll
    for (int p = 0; p < 4; ++p) {
        const int gpos = base + p;
        const int b = gpos / L, l = gpos % L;
        q4[p] = (l == 0) ? cseqs[b * L1] : shft_cseqs[b * L1 + l - 1];
    }

    #pragma unroll
    for (int p = 0; p < 4; ++p) {
        const int gpos = base + p;
        float rd = 0.f;
        #pragma unroll
        for (int ch = 0; ch < NCH; ++ch)
            rd += rp[((size_t)gpos * NCH + ch) * D + lane];
        const float kt = ktab[(size_t)q4[p] * D + lane];

        lrd[lane] = rd;                       // intra-wave LDS transpose-broadcast
        float f0 = 0.f;                       // single ascending chain (as before)
        #pragma unroll
        for (int i = 0; i < D; i += 4) {
            const float4 rb = *(const float4*)&lrd[i];   // uniform -> broadcast
            f0 = fmaf(Wf_c[i],     rb.x, f0);
            f0 = fmaf(Wf_c[i + 1], rb.y, f0);
            f0 = fmaf(Wf_c[i + 2], rb.z, f0);
            f0 = fmaf(Wf_c[i + 3], rb.w, f0);
        }
        const float f = tanhf(f0 + kt + bf_r);

        float c = f * wp_r;
        #pragma unroll
        for (int off = 32; off; off >>= 1) c += __shfl_xor(c, off, 64);
        if (lane == 0) out[gpos] = 1.f / (1.f + expf(-(c + bp_r)));
    }
}

extern "C" void kernel_launch(void* const* d_in, const int* in_sizes, int n_in,
                              void* d_out, int out_size, void* d_ws, size_t ws_size,
                              hipStream_t stream) {
    const int*   cseqs      = (const int*)d_in[0];
    const int*   rseqs      = (const int*)d_in[1];
    const int*   shft_cseqs = (const int*)d_in[2];
    const int*   shft_rseqs = (const int*)d_in[3];
    const float* kemb = (const float*)d_in[4];
    const float* vemb = (const float*)d_in[5];
    const float* Mk   = (const float*)d_in[6];
    const float* Mv0  = (const float*)d_in[7];
    const float* Wf   = (const float*)d_in[8];
    const float* bf   = (const float*)d_in[9];
    const float* We   = (const float*)d_in[10];
    const float* be   = (const float*)d_in[11];
    const float* Wa   = (const float*)d_in[12];
    const float* ba   = (const float*)d_in[13];
    const float* Wp   = (const float*)d_in[14];
    const float* bp   = (const float*)d_in[15];
    float* out = (float*)d_out;

    float* ws   = (float*)d_ws;
    float* wtab = ws;                       // 1000*50  =   50000 floats
    float* etab = wtab + (size_t)NC * M;    // 2000*64  =  128000
    float* atab = etab + (size_t)2 * NC * D;// 2000*64  =  128000
    float* ktab = atab + (size_t)2 * NC * D;// 1000*64  =   64000
    float* rp   = ktab + (size_t)NC * D;    // B*L*NCH*D = 8192000  (~34 MB total)

    phase0<<<dim3(1500), dim3(64), 0, stream>>>(
        kemb, vemb, Mk, We, be, Wa, ba, Wf, wtab, etab, atab, ktab);
    phase2<<<dim3(B * NCH), dim3(64), 0, stream>>>(
        Mv0, cseqs, rseqs, shft_cseqs, shft_rseqs, wtab, etab, atab, rp);
    phase3<<<dim3(800), dim3(256), 0, stream>>>(
        cseqs, shft_cseqs, ktab, Wf, bf, Wp, bp, rp, out);
}

// Round 3
// 127.433 us; speedup vs baseline: 1.3133x; 1.0031x over previous
//
#include <hip/hip_runtime.h>
#include <math.h>

#define B    64
#define L1   199
#define L    200
#define NC   1000
#define D    64
#define M    50
#define NCH  10     // m-chunks in the scan
#define MC   5      // m per chunk (NCH*MC = M)
#define SEG  4      // time segments (L/SEG = TS)
#define TS   50     // t per segment

// ---------------- Phase 0: build id-indexed tables (token-id -> row).
// Block ranges (4 rows per single-wave block):
//   [0,250):     wtab[q][m]  = softmax(kemb[q] @ Mk^T)
//   [250,750):   etab[x][d]  = sigmoid(vemb[x] @ We + be)
//   [750,1250):  atab[x][d]  = tanh   (vemb[x] @ Wa + ba)
//   [1250,1500): ktab[q][d]  = kemb[q] @ Wf[D:2D]   (phase3 k-half)
__global__ __launch_bounds__(64) void phase0(
    const float* __restrict__ kemb, const float* __restrict__ vemb,
    const float* __restrict__ Mk,
    const float* __restrict__ We, const float* __restrict__ be,
    const float* __restrict__ Wa, const float* __restrict__ ba,
    const float* __restrict__ Wf,
    float* __restrict__ wtab, float* __restrict__ etab,
    float* __restrict__ atab, float* __restrict__ ktab)
{
    __shared__ __align__(16) float lrow[4 * D];
    const int lane = threadIdx.x;
    const int bid  = blockIdx.x;

    if (bid < 250) {
        const int r0 = bid * 4;
        #pragma unroll
        for (int i = 0; i < 4; ++i)
            lrow[i * D + lane] = kemb[(size_t)(r0 + i) * D + lane];
        __syncthreads();

        float Mk_r[D];
        {
            const int mrow = (lane < M) ? lane : (M - 1);
            #pragma unroll
            for (int d = 0; d < D; d += 4) {
                const float4 t4 = *(const float4*)(Mk + mrow * D + d);
                Mk_r[d] = t4.x; Mk_r[d+1] = t4.y; Mk_r[d+2] = t4.z; Mk_r[d+3] = t4.w;
            }
        }
        #pragma unroll
        for (int i = 0; i < 4; ++i) {
            float c0 = 0.f, c1 = 0.f;
            #pragma unroll
            for (int d = 0; d < D; d += 4) {
                const float4 kb = *(const float4*)&lrow[i * D + d];
                c0 = fmaf(Mk_r[d],     kb.x, c0);
                c1 = fmaf(Mk_r[d + 1], kb.y, c1);
                c0 = fmaf(Mk_r[d + 2], kb.z, c0);
                c1 = fmaf(Mk_r[d + 3], kb.w, c1);
            }
            const float logit = (lane < M) ? (c0 + c1) : -INFINITY;
            float mx = logit;
            #pragma unroll
            for (int off = 32; off; off >>= 1) mx = fmaxf(mx, __shfl_xor(mx, off, 64));
            const float ex = expf(logit - mx);
            float sm = ex;
            #pragma unroll
            for (int off = 32; off; off >>= 1) sm += __shfl_xor(sm, off, 64);
            if (lane < M) wtab[(size_t)(r0 + i) * M + lane] = ex / sm;
        }
    } else if (bid < 1250) {
        const bool is_e = (bid < 750);
        const int  r0   = (is_e ? (bid - 250) : (bid - 750)) * 4;
        #pragma unroll
        for (int i = 0; i < 4; ++i)
            lrow[i * D + lane] = vemb[(size_t)(r0 + i) * D + lane];
        __syncthreads();

        const float* __restrict__ W   = is_e ? We : Wa;
        float*       __restrict__ dst = is_e ? etab : atab;
        float Wc[D];
        #pragma unroll
        for (int din = 0; din < D; ++din) Wc[din] = W[din * D + lane];
        const float br = is_e ? be[lane] : ba[lane];

        #pragma unroll
        for (int i = 0; i < 4; ++i) {
            float c0 = 0.f, c1 = 0.f;
            #pragma unroll
            for (int d = 0; d < D; d += 4) {
                const float4 vb = *(const float4*)&lrow[i * D + d];
                c0 = fmaf(Wc[d],     vb.x, c0);
                c1 = fmaf(Wc[d + 1], vb.y, c1);
                c0 = fmaf(Wc[d + 2], vb.z, c0);
                c1 = fmaf(Wc[d + 3], vb.w, c1);
            }
            const float acc = c0 + c1;
            const float r = is_e ? (1.f / (1.f + expf(-(acc + br))))
                                 : tanhf(acc + br);
            dst[(size_t)(r0 + i) * D + lane] = r;
        }
    } else {
        const int r0 = (bid - 1250) * 4;
        #pragma unroll
        for (int i = 0; i < 4; ++i)
            lrow[i * D + lane] = kemb[(size_t)(r0 + i) * D + lane];
        __syncthreads();

        float Wc[D];
        #pragma unroll
        for (int i = 0; i < D; ++i) Wc[i] = Wf[(size_t)(D + i) * D + lane];

        #pragma unroll
        for (int i = 0; i < 4; ++i) {
            float f1 = 0.f;
            #pragma unroll
            for (int d = 0; d < D; d += 4) {
                const float4 kb = *(const float4*)&lrow[i * D + d];
                f1 = fmaf(Wc[d],     kb.x, f1);
                f1 = fmaf(Wc[d + 1], kb.y, f1);
                f1 = fmaf(Wc[d + 2], kb.z, f1);
                f1 = fmaf(Wc[d + 3], kb.w, f1);
            }
            ktab[(size_t)(r0 + i) * D + lane] = f1;
        }
    }
}

// ---------------- scanA: per (b, m-chunk, seg in [0,3)) compute the affine
// composition of the segment: Mv_end = A (.) Mv_start + Bv.
// Same staging structure as the scan; same update form, applied to (A,Bv).
__global__ __launch_bounds__(64) void scanA(
    const int* __restrict__ cseqs, const int* __restrict__ rseqs,
    const int* __restrict__ shft_cseqs, const int* __restrict__ shft_rseqs,
    const float* __restrict__ wtab, const float* __restrict__ etab,
    const float* __restrict__ atab,
    float* __restrict__ abuf, float* __restrict__ bbuf)
{
    __shared__ __align__(16) float lds_w[TS * 8];
    const int lane = threadIdx.x;
    const int s  = blockIdx.x % 3;          // segments 0..2 (seg 3 never needed)
    const int bc = blockIdx.x / 3;          // b*NCH + ch
    const int b  = bc / NCH;
    const int ch = bc % NCH;
    const int m0 = ch * MC;
    const int t0 = s * TS;

    int ql = 0, xl = 0;
    if (lane < TS) {
        const int t = t0 + lane;
        int q, r;
        if (t == 0) { q = cseqs[b * L1];              r = rseqs[b * L1]; }
        else        { q = shft_cseqs[b * L1 + t - 1]; r = shft_rseqs[b * L1 + t - 1]; }
        ql = q; xl = q + NC * r;
    }
    if (lane < TS) {
        const float* __restrict__ wp = wtab + (size_t)ql * M + m0;
        #pragma unroll
        for (int j = 0; j < MC; ++j) lds_w[lane * 8 + j] = wp[j];
    }
    float er[TS], ar[TS];
    #pragma unroll
    for (int t = 0; t < TS; ++t) {
        const int sx = __builtin_amdgcn_readlane(xl, t);
        er[t] = etab[(size_t)sx * D + lane];
        ar[t] = atab[(size_t)sx * D + lane];
    }
    __syncthreads();

    float A0=1.f,A1=1.f,A2=1.f,A3=1.f,A4=1.f;
    float B0=0.f,B1=0.f,B2=0.f,B3=0.f,B4=0.f;

    #pragma unroll
    for (int t = 0; t < TS; ++t) {
        const float4 w4 = *(const float4*)&lds_w[t * 8];
        const float wm0 = w4.x, wm1 = w4.y, wm2 = w4.z, wm3 = w4.w;
        const float wm4 = lds_w[t * 8 + 4];
        const float ed = er[t], ad = ar[t];
        A0 = fmaf(A0, -(wm0 * ed), A0); B0 = fmaf(B0, -(wm0 * ed), fmaf(wm0, ad, B0));
        A1 = fmaf(A1, -(wm1 * ed), A1); B1 = fmaf(B1, -(wm1 * ed), fmaf(wm1, ad, B1));
        A2 = fmaf(A2, -(wm2 * ed), A2); B2 = fmaf(B2, -(wm2 * ed), fmaf(wm2, ad, B2));
        A3 = fmaf(A3, -(wm3 * ed), A3); B3 = fmaf(B3, -(wm3 * ed), fmaf(wm3, ad, B3));
        A4 = fmaf(A4, -(wm4 * ed), A4); B4 = fmaf(B4, -(wm4 * ed), fmaf(wm4, ad, B4));
    }
    float* __restrict__ ap = abuf + ((size_t)bc * 3 + s) * MC * D + lane;
    float* __restrict__ bp = bbuf + ((size_t)bc * 3 + s) * MC * D + lane;
    ap[0 * D] = A0; ap[1 * D] = A1; ap[2 * D] = A2; ap[3 * D] = A3; ap[4 * D] = A4;
    bp[0 * D] = B0; bp[1 * D] = B1; bp[2 * D] = B2; bp[3 * D] = B3; bp[4 * D] = B4;
}

// ---------------- scanB: per (b, m-chunk, seg in [0,4)) reconstruct the segment
// start state by composing preceding (A,Bv), then run the 50-step scan emitting
// read partials. Inner loop is bit-identical to the previously passing phase2.
__global__ __launch_bounds__(64) void scanB(
    const float* __restrict__ Mv0,
    const int* __restrict__ cseqs, const int* __restrict__ rseqs,
    const int* __restrict__ shft_cseqs, const int* __restrict__ shft_rseqs,
    const float* __restrict__ wtab, const float* __restrict__ etab,
    const float* __restrict__ atab,
    const float* __restrict__ abuf, const float* __restrict__ bbuf,
    float* __restrict__ rp_out)
{
    __shared__ __align__(16) float lds_w[TS * 8];
    const int lane = threadIdx.x;
    const int s  = blockIdx.x % SEG;
    const int bc = blockIdx.x / SEG;        // b*NCH + ch
    const int b  = bc / NCH;
    const int ch = bc % NCH;
    const int m0 = ch * MC;
    const int t0 = s * TS;

    int ql = 0, xl = 0;
    if (lane < TS) {
        const int t = t0 + lane;
        int q, r;
        if (t == 0) { q = cseqs[b * L1];              r = rseqs[b * L1]; }
        else        { q = shft_cseqs[b * L1 + t - 1]; r = shft_rseqs[b * L1 + t - 1]; }
        ql = q; xl = q + NC * r;
    }
    if (lane < TS) {
        const float* __restrict__ wp = wtab + (size_t)ql * M + m0;
        #pragma unroll
        for (int j = 0; j < MC; ++j) lds_w[lane * 8 + j] = wp[j];
    }
    float er[TS], ar[TS];
    #pragma unroll
    for (int t = 0; t < TS; ++t) {
        const int sx = __builtin_amdgcn_readlane(xl, t);
        er[t] = etab[(size_t)sx * D + lane];
        ar[t] = atab[(size_t)sx * D + lane];
    }

    float Mv[MC];
    #pragma unroll
    for (int j = 0; j < MC; ++j) Mv[j] = Mv0[(m0 + j) * D + lane];
    // prefix combine: apply preceding segments' affine maps in order
    for (int ss = 0; ss < s; ++ss) {
        const float* __restrict__ ap = abuf + ((size_t)bc * 3 + ss) * MC * D + lane;
        const float* __restrict__ bp = bbuf + ((size_t)bc * 3 + ss) * MC * D + lane;
        #pragma unroll
        for (int j = 0; j < MC; ++j) Mv[j] = fmaf(ap[j * D], Mv[j], bp[j * D]);
    }
    __syncthreads();

    float* __restrict__ rp = rp_out + ((size_t)b * L * NCH + ch) * D + lane;

    #pragma unroll
    for (int t = 0; t < TS; ++t) {
        const float4 w4 = *(const float4*)&lds_w[t * 8];
        const float wm0 = w4.x, wm1 = w4.y, wm2 = w4.z, wm3 = w4.w;
        const float wm4 = lds_w[t * 8 + 4];
        const float ed = er[t], ad = ar[t];
        float r0 = 0.f, r1 = 0.f;
        r0 = fmaf(wm0, Mv[0], r0); Mv[0] = fmaf(Mv[0], -(wm0 * ed), fmaf(wm0, ad, Mv[0]));
        r1 = fmaf(wm1, Mv[1], r1); Mv[1] = fmaf(Mv[1], -(wm1 * ed), fmaf(wm1, ad, Mv[1]));
        r0 = fmaf(wm2, Mv[2], r0); Mv[2] = fmaf(Mv[2], -(wm2 * ed), fmaf(wm2, ad, Mv[2]));
        r1 = fmaf(wm3, Mv[3], r1); Mv[3] = fmaf(Mv[3], -(wm3 * ed), fmaf(wm3, ad, Mv[3]));
        r0 = fmaf(wm4, Mv[4], r0); Mv[4] = fmaf(Mv[4], -(wm4 * ed), fmaf(wm4, ad, Mv[4]));
        rp[(size_t)(t0 + t) * NCH * D] = r0 + r1;
    }
}

// ---------------- Phase 3: read = sum partials; f = tanh(read@Wf1 + ktab[q] + bf);
// p = sigmoid(f@Wp+bp). rd broadcast via per-wave LDS row.
__global__ __launch_bounds__(256, 1) void phase3(
    const int* __restrict__ cseqs, const int* __restrict__ shft_cseqs,
    const float* __restrict__ ktab,
    const float* __restrict__ Wf, const float* __restrict__ bf,
    const float* __restrict__ Wp, const float* __restrict__ bp,
    const float* __restrict__ rp, float* __restrict__ out)
{
    __shared__ __align__(16) float lds_rd[4 * D];
    const int tid  = threadIdx.x;
    const int lane = tid & 63;
    const int wave = tid >> 6;
    float* __restrict__ lrd = lds_rd + wave * D;

    float Wf_c[D];
    #pragma unroll
    for (int i = 0; i < D; ++i) Wf_c[i] = Wf[(size_t)i * D + lane];
    const float bf_r = bf[lane];
    const float wp_r = Wp[lane];
    const float bp_r = bp[0];

    const int base = blockIdx.x * 16 + wave * 4;

    int q4[4];
    #pragma unroll
    for (int p = 0; p < 4; ++p) {
        const int gpos = base + p;
        const int b = gpos / L, l = gpos % L;
        q4[p] = (l == 0) ? cseqs[b * L1] : shft_cseqs[b * L1 + l - 1];
    }

    #pragma unroll
    for (int p = 0; p < 4; ++p) {
        const int gpos = base + p;
        float rd = 0.f;
        #pragma unroll
        for (int ch = 0; ch < NCH; ++ch)
            rd += rp[((size_t)gpos * NCH + ch) * D + lane];
        const float kt = ktab[(size_t)q4[p] * D + lane];

        lrd[lane] = rd;
        float f0 = 0.f;
        #pragma unroll
        for (int i = 0; i < D; i += 4) {
            const float4 rb = *(const float4*)&lrd[i];
            f0 = fmaf(Wf_c[i],     rb.x, f0);
            f0 = fmaf(Wf_c[i + 1], rb.y, f0);
            f0 = fmaf(Wf_c[i + 2], rb.z, f0);
            f0 = fmaf(Wf_c[i + 3], rb.w, f0);
        }
        const float f = tanhf(f0 + kt + bf_r);

        float c = f * wp_r;
        #pragma unroll
        for (int off = 32; off; off >>= 1) c += __shfl_xor(c, off, 64);
        if (lane == 0) out[gpos] = 1.f / (1.f + expf(-(c + bp_r)));
    }
}

extern "C" void kernel_launch(void* const* d_in, const int* in_sizes, int n_in,
                              void* d_out, int out_size, void* d_ws, size_t ws_size,
                              hipStream_t stream) {
    const int*   cseqs      = (const int*)d_in[0];
    const int*   rseqs      = (const int*)d_in[1];
    const int*   shft_cseqs = (const int*)d_in[2];
    const int*   shft_rseqs = (const int*)d_in[3];
    const float* kemb = (const float*)d_in[4];
    const float* vemb = (const float*)d_in[5];
    const float* Mk   = (const float*)d_in[6];
    const float* Mv0  = (const float*)d_in[7];
    const float* Wf   = (const float*)d_in[8];
    const float* bf   = (const float*)d_in[9];
    const float* We   = (const float*)d_in[10];
    const float* be   = (const float*)d_in[11];
    const float* Wa   = (const float*)d_in[12];
    const float* ba   = (const float*)d_in[13];
    const float* Wp   = (const float*)d_in[14];
    const float* bp   = (const float*)d_in[15];
    float* out = (float*)d_out;

    float* ws   = (float*)d_ws;
    float* wtab = ws;                         // 1000*50  =   50000 floats
    float* etab = wtab + (size_t)NC * M;      // 2000*64  =  128000
    float* atab = etab + (size_t)2 * NC * D;  // 2000*64  =  128000
    float* ktab = atab + (size_t)2 * NC * D;  // 1000*64  =   64000
    float* rp   = ktab + (size_t)NC * D;      // B*L*NCH*D = 8192000
    float* abuf = rp   + (size_t)B * L * NCH * D;  // B*NCH*3*MC*D = 614400
    float* bbuf = abuf + (size_t)B * NCH * 3 * MC * D; // 614400   (~39 MB total)

    phase0<<<dim3(1500), dim3(64), 0, stream>>>(
        kemb, vemb, Mk, We, be, Wa, ba, Wf, wtab, etab, atab, ktab);
    scanA<<<dim3(B * NCH * 3), dim3(64), 0, stream>>>(
        cseqs, rseqs, shft_cseqs, shft_rseqs, wtab, etab, atab, abuf, bbuf);
    scanB<<<dim3(B * NCH * SEG), dim3(64), 0, stream>>>(
        Mv0, cseqs, rseqs, shft_cseqs, shft_rseqs, wtab, etab, atab,
        abuf, bbuf, rp);
    phase3<<<dim3(800), dim3(256), 0, stream>>>(
        cseqs, shft_cseqs, ktab, Wf, bf, Wp, bp, rp, out);
}